// Round 1
// baseline (228.595 us; speedup 1.0000x reference)
//
#include <hip/hip_runtime.h>
#include <math.h>

#define B 64
#define S 512
#define H 768
#define U 16
#define C 5
#define M (B*U)          // 1024 segments
#define SCH 32           // tokens per block in segment-reduce
#define TM 64
#define TN 64
#define TK 16

// ---------------------------------------------------------------------------
// Kernel 1: per-(batch,utterance) segment sums + counts.
// segment_ids are sorted per batch row -> within a contiguous token chunk the
// segment id is wave-uniform; accumulate in registers, atomically flush only
// at segment boundaries. 192 threads, each owns 4 consecutive h-dims (float4).
// ---------------------------------------------------------------------------
__global__ __launch_bounds__(192) void seg_reduce_kernel(
    const float* __restrict__ hidden, const int* __restrict__ seg,
    float* __restrict__ sums, float* __restrict__ counts)
{
    const int b     = blockIdx.x >> 4;        // S/SCH = 16 chunks per batch row
    const int chunk = blockIdx.x & 15;
    const int s0    = chunk * SCH;
    const int t     = threadIdx.x;            // 0..191
    const float4* h4 = (const float4*)(hidden + (size_t)b * S * H);

    float4 acc = make_float4(0.f, 0.f, 0.f, 0.f);
    int cnt = 0;
    int cur = seg[b * S + s0];

    for (int s = s0; s < s0 + SCH; ++s) {
        int sg = seg[b * S + s];              // uniform across block
        if (sg != cur) {
            float* dst = sums + (size_t)(b * U + cur) * H + t * 4;
            atomicAdd(dst + 0, acc.x); atomicAdd(dst + 1, acc.y);
            atomicAdd(dst + 2, acc.z); atomicAdd(dst + 3, acc.w);
            if (t == 0) atomicAdd(counts + b * U + cur, (float)cnt);
            acc = make_float4(0.f, 0.f, 0.f, 0.f);
            cnt = 0;
            cur = sg;
        }
        float4 v = h4[(size_t)s * (H / 4) + t];
        acc.x += v.x; acc.y += v.y; acc.z += v.z; acc.w += v.w;
        ++cnt;
    }
    float* dst = sums + (size_t)(b * U + cur) * H + t * 4;
    atomicAdd(dst + 0, acc.x); atomicAdd(dst + 1, acc.y);
    atomicAdd(dst + 2, acc.z); atomicAdd(dst + 3, acc.w);
    if (t == 0) atomicAdd(counts + b * U + cur, (float)cnt);
}

// ---------------------------------------------------------------------------
// Kernel 2: means = sums/max(count,1) fused into A-load; C = selu(A@Wh + bh).
// fp32 vector GEMM, 64x64 tile, 256 threads, 4x4 microtile, TK=16.
// ---------------------------------------------------------------------------
__global__ __launch_bounds__(256) void gemm1_selu_kernel(
    const float* __restrict__ sums, const float* __restrict__ counts,
    const float* __restrict__ Wh, const float* __restrict__ bh,
    float* __restrict__ hout)
{
    __shared__ float As[TK][TM];   // [k][m]
    __shared__ float Bs[TK][TN];   // [k][n]
    __shared__ float inv[TM];

    const int bm = blockIdx.x & 15;        // M/TM = 16
    const int bn = blockIdx.x >> 4;        // H/TN = 12
    const int m0 = bm * TM, n0 = bn * TN;
    const int tid = threadIdx.x;

    if (tid < TM) {
        float c = counts[m0 + tid];
        inv[tid] = 1.0f / fmaxf(c, 1.0f);
    }
    __syncthreads();

    const int tx = tid & 15;               // n-group (4 cols)
    const int ty = tid >> 4;               // m-group (4 rows)
    const int am = tid >> 2;               // A stage: row 0..63
    const int ak = (tid & 3) * 4;          // A stage: k offset 0,4,8,12
    const int bk  = tid >> 4;              // B stage: k row 0..15
    const int bn4 = (tid & 15) * 4;        // B stage: n offset

    float c[4][4] = {};

    for (int k0 = 0; k0 < H; k0 += TK) {
        const float4 a = *(const float4*)(sums + (size_t)(m0 + am) * H + k0 + ak);
        float sc = inv[am];
        As[ak + 0][am] = a.x * sc;
        As[ak + 1][am] = a.y * sc;
        As[ak + 2][am] = a.z * sc;
        As[ak + 3][am] = a.w * sc;
        *(float4*)&Bs[bk][bn4] = *(const float4*)(Wh + (size_t)(k0 + bk) * H + n0 + bn4);
        __syncthreads();

        #pragma unroll
        for (int k = 0; k < TK; ++k) {
            float4 av = *(const float4*)&As[k][ty * 4];
            float4 bv = *(const float4*)&Bs[k][tx * 4];
            float aa[4] = {av.x, av.y, av.z, av.w};
            float bb[4] = {bv.x, bv.y, bv.z, bv.w};
            #pragma unroll
            for (int i = 0; i < 4; ++i)
                #pragma unroll
                for (int j = 0; j < 4; ++j)
                    c[i][j] += aa[i] * bb[j];
        }
        __syncthreads();
    }

    const float SC = 1.0507009873554805f, AL = 1.6732632423543772f;
    #pragma unroll
    for (int i = 0; i < 4; ++i) {
        int m = m0 + ty * 4 + i;
        #pragma unroll
        for (int j = 0; j < 4; ++j) {
            int n = n0 + tx * 4 + j;
            float x = c[i][j] + bh[n];
            float y = x > 0.f ? SC * x : SC * AL * (expf(x) - 1.f);
            hout[(size_t)m * H + n] = y;
        }
    }
}

// ---------------------------------------------------------------------------
// Kernel 3: logits = h @ Wo + bo, softmax over C=5. One wave per row.
// ---------------------------------------------------------------------------
__global__ __launch_bounds__(256) void head_kernel(
    const float* __restrict__ hbuf, const float* __restrict__ Wo,
    const float* __restrict__ bo, float* __restrict__ out)
{
    const int wave = threadIdx.x >> 6;
    const int lane = threadIdx.x & 63;
    const int row  = blockIdx.x * 4 + wave;    // grid 256 -> 1024 rows

    float acc[C] = {};
    #pragma unroll
    for (int j = 0; j < H / 64; ++j) {
        int k = lane + 64 * j;
        float hv = hbuf[(size_t)row * H + k];
        #pragma unroll
        for (int cc = 0; cc < C; ++cc) acc[cc] += hv * Wo[k * C + cc];
    }
    #pragma unroll
    for (int off = 32; off >= 1; off >>= 1)
        #pragma unroll
        for (int cc = 0; cc < C; ++cc) acc[cc] += __shfl_down(acc[cc], off);

    if (lane == 0) {
        float l[C], mx = -1e30f;
        #pragma unroll
        for (int cc = 0; cc < C; ++cc) { l[cc] = acc[cc] + bo[cc]; mx = fmaxf(mx, l[cc]); }
        float sum = 0.f;
        #pragma unroll
        for (int cc = 0; cc < C; ++cc) { l[cc] = expf(l[cc] - mx); sum += l[cc]; }
        float r = 1.0f / sum;
        #pragma unroll
        for (int cc = 0; cc < C; ++cc) out[(size_t)row * C + cc] = l[cc] * r;
    }
}

// ---------------------------------------------------------------------------
extern "C" void kernel_launch(void* const* d_in, const int* in_sizes, int n_in,
                              void* d_out, int out_size, void* d_ws, size_t ws_size,
                              hipStream_t stream)
{
    const float* hidden = (const float*)d_in[0];
    const int*   seg    = (const int*)d_in[1];
    // d_in[2] = n_utter scalar, compile-time U
    const float* Wh = (const float*)d_in[3];
    const float* bh = (const float*)d_in[4];
    const float* Wo = (const float*)d_in[5];
    const float* bo = (const float*)d_in[6];
    float* out = (float*)d_out;

    float* sums   = (float*)d_ws;                   // M*H fp32
    float* counts = sums + (size_t)M * H;           // M fp32
    float* hbuf   = counts + M;                     // M*H fp32

    hipMemsetAsync(d_ws, 0, ((size_t)M * H + M) * sizeof(float), stream);
    seg_reduce_kernel<<<B * (S / SCH), 192, 0, stream>>>(hidden, seg, sums, counts);
    gemm1_selu_kernel<<<(M / TM) * (H / TN), 256, 0, stream>>>(sums, counts, Wh, bh, hbuf);
    head_kernel<<<M / 4, 256, 0, stream>>>(hbuf, Wo, bo, out);
}

// Round 2
// 192.324 us; speedup vs baseline: 1.1886x; 1.1886x over previous
//
#include <hip/hip_runtime.h>
#include <math.h>

#define B 64
#define S 512
#define H 768
#define U 16
#define C 5
#define M (B*U)          // 1024 segments

typedef __attribute__((ext_vector_type(8))) short short8;
typedef __attribute__((ext_vector_type(4))) float floatx4;

__device__ inline unsigned short f2bf(float x) {          // round-to-nearest-even
    unsigned u = __float_as_uint(x);
    u += 0x7FFFu + ((u >> 16) & 1u);
    return (unsigned short)(u >> 16);
}

// ---------------------------------------------------------------------------
// Kernel 1: per-(b,u) mean via binary search over the sorted seg row.
// One block per segment; 192 threads x float4 = 768 floats per token.
// Branch-free load loop -> deep pipelining. Writes means directly as bf16.
// ---------------------------------------------------------------------------
__global__ __launch_bounds__(192) void seg_mean_kernel(
    const float* __restrict__ hidden, const int* __restrict__ seg,
    unsigned short* __restrict__ means)
{
    const int b = blockIdx.x >> 4;     // U = 16
    const int u = blockIdx.x & 15;
    const int* srow = seg + b * S;

    // lower_bound(u) and lower_bound(u+1) — wave-uniform
    int lo = 0, hi = S;
    while (lo < hi) { int mid = (lo + hi) >> 1; if (srow[mid] < u) lo = mid + 1; else hi = mid; }
    const int start = lo;
    hi = S;
    while (lo < hi) { int mid = (lo + hi) >> 1; if (srow[mid] < u + 1) lo = mid + 1; else hi = mid; }
    const int end = lo;

    const int t = threadIdx.x;         // 0..191
    const float4* h4 = (const float4*)(hidden + (size_t)b * S * H);

    float4 acc = make_float4(0.f, 0.f, 0.f, 0.f);
    for (int s = start; s < end; ++s) {
        float4 v = h4[(size_t)s * (H / 4) + t];
        acc.x += v.x; acc.y += v.y; acc.z += v.z; acc.w += v.w;
    }
    const float inv = 1.0f / fmaxf((float)(end - start), 1.0f);
    ushort4 o;
    o.x = f2bf(acc.x * inv); o.y = f2bf(acc.y * inv);
    o.z = f2bf(acc.z * inv); o.w = f2bf(acc.w * inv);
    ((ushort4*)(means + (size_t)(b * U + u) * H))[t] = o;
}

// ---------------------------------------------------------------------------
// Kernel 2: Wht_bf16[n][k] = bf16(Wh[k][n]) — LDS tiled transpose + convert.
// ---------------------------------------------------------------------------
__global__ __launch_bounds__(256) void wh_transpose_kernel(
    const float* __restrict__ Wh, unsigned short* __restrict__ Bt)
{
    __shared__ float tile[32][33];
    const int bn = blockIdx.x % (H / 32);   // n-tile
    const int bk = blockIdx.x / (H / 32);   // k-tile
    const int tx = threadIdx.x & 31;
    const int ty = threadIdx.x >> 5;        // 0..7
    #pragma unroll
    for (int i = 0; i < 4; ++i)
        tile[ty + 8 * i][tx] = Wh[(size_t)(bk * 32 + ty + 8 * i) * H + bn * 32 + tx];
    __syncthreads();
    #pragma unroll
    for (int i = 0; i < 4; ++i)
        Bt[(size_t)(bn * 32 + ty + 8 * i) * H + bk * 32 + tx] = f2bf(tile[tx][ty + 8 * i]);
}

// ---------------------------------------------------------------------------
// Kernel 3: hout = selu(means @ Wh + bh) via bf16 MFMA 16x16x32, fp32 acc.
// No LDS: fragments stream from L2. 4 waves/block, one 16x16 tile per wave.
// A-frag: lane holds A[m=lane&15][k=quad*8+j]; B-frag: B[k=quad*8+j][n=lane&15]
// (Bt is [N][K] so both are contiguous 16B loads). C/D: col=lane&15, row=quad*4+r.
// ---------------------------------------------------------------------------
__global__ __launch_bounds__(256) void gemm1_mfma_kernel(
    const unsigned short* __restrict__ means, const unsigned short* __restrict__ Bt,
    const float* __restrict__ bh, float* __restrict__ hout)
{
    const int wid  = threadIdx.x >> 6;
    const int lane = threadIdx.x & 63;
    const int tile = blockIdx.x * 4 + wid;      // 64*48 = 3072 wave-tiles
    const int tm = tile / (H / 16);             // 0..63
    const int tn = tile % (H / 16);             // 0..47
    const int m0 = tm * 16, n0 = tn * 16;

    const int quad = lane >> 4;
    const int l16  = lane & 15;

    const short8* ap = (const short8*)(means + (size_t)(m0 + l16) * H);
    const short8* bp = (const short8*)(Bt    + (size_t)(n0 + l16) * H);

    floatx4 acc = {0.f, 0.f, 0.f, 0.f};
    #pragma unroll 8
    for (int kk = 0; kk < H / 32; ++kk) {
        short8 a = ap[4 * kk + quad];
        short8 b = bp[4 * kk + quad];
        acc = __builtin_amdgcn_mfma_f32_16x16x32_bf16(a, b, acc, 0, 0, 0);
    }

    const float SC = 1.0507009873554805f, AL = 1.6732632423543772f;
    const float bsum = bh[n0 + l16];
    #pragma unroll
    for (int r = 0; r < 4; ++r) {
        float x = acc[r] + bsum;
        float y = x > 0.f ? SC * x : SC * AL * (expf(x) - 1.f);
        hout[(size_t)(m0 + quad * 4 + r) * H + n0 + l16] = y;
    }
}

// ---------------------------------------------------------------------------
// Kernel 4: logits = h @ Wo + bo, softmax over C=5. One wave per row.
// ---------------------------------------------------------------------------
__global__ __launch_bounds__(256) void head_kernel(
    const float* __restrict__ hbuf, const float* __restrict__ Wo,
    const float* __restrict__ bo, float* __restrict__ out)
{
    const int wave = threadIdx.x >> 6;
    const int lane = threadIdx.x & 63;
    const int row  = blockIdx.x * 4 + wave;

    float acc[C] = {};
    #pragma unroll
    for (int j = 0; j < H / 64; ++j) {
        int k = lane + 64 * j;
        float hv = hbuf[(size_t)row * H + k];
        #pragma unroll
        for (int cc = 0; cc < C; ++cc) acc[cc] += hv * Wo[k * C + cc];
    }
    #pragma unroll
    for (int off = 32; off >= 1; off >>= 1)
        #pragma unroll
        for (int cc = 0; cc < C; ++cc) acc[cc] += __shfl_down(acc[cc], off);

    if (lane == 0) {
        float l[C], mx = -1e30f;
        #pragma unroll
        for (int cc = 0; cc < C; ++cc) { l[cc] = acc[cc] + bo[cc]; mx = fmaxf(mx, l[cc]); }
        float sum = 0.f;
        #pragma unroll
        for (int cc = 0; cc < C; ++cc) { l[cc] = expf(l[cc] - mx); sum += l[cc]; }
        float r = 1.0f / sum;
        #pragma unroll
        for (int cc = 0; cc < C; ++cc) out[(size_t)row * C + cc] = l[cc] * r;
    }
}

// ---------------------------------------------------------------------------
extern "C" void kernel_launch(void* const* d_in, const int* in_sizes, int n_in,
                              void* d_out, int out_size, void* d_ws, size_t ws_size,
                              hipStream_t stream)
{
    const float* hidden = (const float*)d_in[0];
    const int*   seg    = (const int*)d_in[1];
    const float* Wh = (const float*)d_in[3];
    const float* bh = (const float*)d_in[4];
    const float* Wo = (const float*)d_in[5];
    const float* bo = (const float*)d_in[6];
    float* out = (float*)d_out;

    // workspace layout (16B-aligned slabs)
    float*          hbuf  = (float*)d_ws;                       // M*H fp32 = 3 MB
    unsigned short* means = (unsigned short*)(hbuf + (size_t)M * H);   // M*H bf16
    unsigned short* Bt    = means + (size_t)M * H;              // H*H bf16

    wh_transpose_kernel<<<(H / 32) * (H / 32), 256, 0, stream>>>(Wh, Bt);
    seg_mean_kernel<<<M, 192, 0, stream>>>(hidden, seg, means);
    gemm1_mfma_kernel<<<(M / 16) * (H / 16) / 4, 256, 0, stream>>>(means, Bt, bh, hbuf);
    head_kernel<<<M / 4, 256, 0, stream>>>(hbuf, Wo, bo, out);
}

// Round 3
// 187.591 us; speedup vs baseline: 1.2186x; 1.0252x over previous
//
#include <hip/hip_runtime.h>
#include <math.h>

#define B 64
#define S 512
#define H 768
#define U 16
#define C 5
#define M (B*U)          // 1024 segments

typedef __attribute__((ext_vector_type(8))) short short8;
typedef __attribute__((ext_vector_type(4))) float floatx4;

__device__ inline unsigned short f2bf(float x) {          // round-to-nearest-even
    unsigned u = __float_as_uint(x);
    u += 0x7FFFu + ((u >> 16) & 1u);
    return (unsigned short)(u >> 16);
}
__device__ inline void acc4(float4& a, const float4& v) {
    a.x += v.x; a.y += v.y; a.z += v.z; a.w += v.w;
}

// ---------------------------------------------------------------------------
// Kernel 1: per-(b,u) mean via binary search over the sorted seg row.
// One block per segment; 192 threads x float4 = 768 floats per token.
// 4 tokens/iter into 4 independent accumulators + unroll 2 -> 8 float4 loads
// in flight per wave (latency -> BW bound). Writes means as bf16.
// ---------------------------------------------------------------------------
__global__ __launch_bounds__(192) void seg_mean_kernel(
    const float* __restrict__ hidden, const int* __restrict__ seg,
    unsigned short* __restrict__ means)
{
    const int b = blockIdx.x >> 4;     // U = 16
    const int u = blockIdx.x & 15;
    const int* srow = seg + b * S;

    int lo = 0, hi = S;                // lower_bound(u)
    while (lo < hi) { int mid = (lo + hi) >> 1; if (srow[mid] < u) lo = mid + 1; else hi = mid; }
    const int start = lo;
    hi = S;                            // lower_bound(u+1)
    while (lo < hi) { int mid = (lo + hi) >> 1; if (srow[mid] < u + 1) lo = mid + 1; else hi = mid; }
    const int end = lo;

    const int t = threadIdx.x;         // 0..191
    const float4* h4 = (const float4*)(hidden + (size_t)b * S * H) + t;
    const int ldr = H / 4;             // float4 row stride

    float4 a0 = make_float4(0.f,0.f,0.f,0.f), a1 = a0, a2 = a0, a3 = a0;
    int s = start;
    #pragma unroll 2
    for (; s + 4 <= end; s += 4) {
        float4 v0 = h4[(size_t)(s + 0) * ldr];
        float4 v1 = h4[(size_t)(s + 1) * ldr];
        float4 v2 = h4[(size_t)(s + 2) * ldr];
        float4 v3 = h4[(size_t)(s + 3) * ldr];
        acc4(a0, v0); acc4(a1, v1); acc4(a2, v2); acc4(a3, v3);
    }
    for (; s < end; ++s) acc4(a0, h4[(size_t)s * ldr]);

    acc4(a0, a1); acc4(a2, a3); acc4(a0, a2);
    const float inv = 1.0f / fmaxf((float)(end - start), 1.0f);
    ushort4 o;
    o.x = f2bf(a0.x * inv); o.y = f2bf(a0.y * inv);
    o.z = f2bf(a0.z * inv); o.w = f2bf(a0.w * inv);
    ((ushort4*)(means + (size_t)(b * U + u) * H))[t] = o;
}

// ---------------------------------------------------------------------------
// Kernel 2: Wht_bf16[n][k] = bf16(Wh[k][n]) — LDS tiled transpose + convert.
// ---------------------------------------------------------------------------
__global__ __launch_bounds__(256) void wh_transpose_kernel(
    const float* __restrict__ Wh, unsigned short* __restrict__ Bt)
{
    __shared__ float tile[32][33];
    const int bn = blockIdx.x % (H / 32);
    const int bk = blockIdx.x / (H / 32);
    const int tx = threadIdx.x & 31;
    const int ty = threadIdx.x >> 5;        // 0..7
    #pragma unroll
    for (int i = 0; i < 4; ++i)
        tile[ty + 8 * i][tx] = Wh[(size_t)(bk * 32 + ty + 8 * i) * H + bn * 32 + tx];
    __syncthreads();
    #pragma unroll
    for (int i = 0; i < 4; ++i)
        Bt[(size_t)(bn * 32 + ty + 8 * i) * H + bk * 32 + tx] = f2bf(tile[tx][ty + 8 * i]);
}

// ---------------------------------------------------------------------------
// Kernel 3: hout = selu(means @ Wh + bh), bf16 MFMA 16x16x32, fp32 acc.
// Each wave owns a 16x32 output tile: one A-frag feeds two B-frags/MFMAs
// (halves A traffic vs round 2). Fragments stream from L2 (A 1.5MB + Bt
// 1.1MB are L2-resident). 1536 waves = 384 blocks.
// ---------------------------------------------------------------------------
__global__ __launch_bounds__(256) void gemm1_mfma_kernel(
    const unsigned short* __restrict__ means, const unsigned short* __restrict__ Bt,
    const float* __restrict__ bh, float* __restrict__ hout)
{
    const int wid  = threadIdx.x >> 6;
    const int lane = threadIdx.x & 63;
    const int tile = blockIdx.x * 4 + wid;      // 0..1535
    const int tm = tile / (H / 32);             // 0..63
    const int tn = tile % (H / 32);             // 0..23
    const int m0 = tm * 16, n0 = tn * 32;

    const int quad = lane >> 4;
    const int l16  = lane & 15;

    const short8* ap  = (const short8*)(means + (size_t)(m0 + l16) * H);
    const short8* bp0 = (const short8*)(Bt    + (size_t)(n0 + l16) * H);
    const short8* bp1 = (const short8*)(Bt    + (size_t)(n0 + 16 + l16) * H);

    floatx4 acc0 = {0.f, 0.f, 0.f, 0.f}, acc1 = acc0;
    #pragma unroll 4
    for (int kk = 0; kk < H / 32; ++kk) {
        short8 a  = ap [4 * kk + quad];
        short8 b0 = bp0[4 * kk + quad];
        short8 b1 = bp1[4 * kk + quad];
        acc0 = __builtin_amdgcn_mfma_f32_16x16x32_bf16(a, b0, acc0, 0, 0, 0);
        acc1 = __builtin_amdgcn_mfma_f32_16x16x32_bf16(a, b1, acc1, 0, 0, 0);
    }

    const float SC = 1.0507009873554805f, AL = 1.6732632423543772f;
    const float bs0 = bh[n0 + l16], bs1 = bh[n0 + 16 + l16];
    #pragma unroll
    for (int r = 0; r < 4; ++r) {
        float* row = hout + (size_t)(m0 + quad * 4 + r) * H;
        float x0 = acc0[r] + bs0;
        float x1 = acc1[r] + bs1;
        row[n0 + l16]      = x0 > 0.f ? SC * x0 : SC * AL * (expf(x0) - 1.f);
        row[n0 + 16 + l16] = x1 > 0.f ? SC * x1 : SC * AL * (expf(x1) - 1.f);
    }
}

// ---------------------------------------------------------------------------
// Kernel 4: logits = h @ Wo + bo, softmax over C=5. One wave per row.
// ---------------------------------------------------------------------------
__global__ __launch_bounds__(256) void head_kernel(
    const float* __restrict__ hbuf, const float* __restrict__ Wo,
    const float* __restrict__ bo, float* __restrict__ out)
{
    const int wave = threadIdx.x >> 6;
    const int lane = threadIdx.x & 63;
    const int row  = blockIdx.x * 4 + wave;

    float acc[C] = {};
    #pragma unroll
    for (int j = 0; j < H / 64; ++j) {
        int k = lane + 64 * j;
        float hv = hbuf[(size_t)row * H + k];
        #pragma unroll
        for (int cc = 0; cc < C; ++cc) acc[cc] += hv * Wo[k * C + cc];
    }
    #pragma unroll
    for (int off = 32; off >= 1; off >>= 1)
        #pragma unroll
        for (int cc = 0; cc < C; ++cc) acc[cc] += __shfl_down(acc[cc], off);

    if (lane == 0) {
        float l[C], mx = -1e30f;
        #pragma unroll
        for (int cc = 0; cc < C; ++cc) { l[cc] = acc[cc] + bo[cc]; mx = fmaxf(mx, l[cc]); }
        float sum = 0.f;
        #pragma unroll
        for (int cc = 0; cc < C; ++cc) { l[cc] = expf(l[cc] - mx); sum += l[cc]; }
        float r = 1.0f / sum;
        #pragma unroll
        for (int cc = 0; cc < C; ++cc) out[(size_t)row * C + cc] = l[cc] * r;
    }
}

// ---------------------------------------------------------------------------
extern "C" void kernel_launch(void* const* d_in, const int* in_sizes, int n_in,
                              void* d_out, int out_size, void* d_ws, size_t ws_size,
                              hipStream_t stream)
{
    const float* hidden = (const float*)d_in[0];
    const int*   seg    = (const int*)d_in[1];
    const float* Wh = (const float*)d_in[3];
    const float* bh = (const float*)d_in[4];
    const float* Wo = (const float*)d_in[5];
    const float* bo = (const float*)d_in[6];
    float* out = (float*)d_out;

    float*          hbuf  = (float*)d_ws;                            // M*H fp32
    unsigned short* means = (unsigned short*)(hbuf + (size_t)M * H); // M*H bf16
    unsigned short* Bt    = means + (size_t)M * H;                   // H*H bf16

    wh_transpose_kernel<<<(H / 32) * (H / 32), 256, 0, stream>>>(Wh, Bt);
    seg_mean_kernel<<<M, 192, 0, stream>>>(hidden, seg, means);
    gemm1_mfma_kernel<<<(M / 16) * (H / 32) / 4, 256, 0, stream>>>(means, Bt, bh, hbuf);
    head_kernel<<<M / 4, 256, 0, stream>>>(hbuf, Wo, bo, out);
}